// Round 7
// baseline (123.400 us; speedup 1.0000x reference)
//
#include <hip/hip_runtime.h>

// out[bc, 2d+k0, 2y+k1, 2z+k2] = x[bc,d,y,z] * p[k0*4+k1*2+k2] + m[...]
// x: (64,64,64,64) fp32, out: (64,128,128,128) fp32.
//
// Thread-unit j: reads x float2 once (NT load), writes dense float4 to both
// k0 planes (out4[o], out4[o+4096]).  j bits: bc(6) | d(6) | Y(7) | Z4(5).
//
// Store policy: NT stores (R6 A/B: plain stores -6%. 537MB >> 32MB L2 —
// streaming/no-allocate wins).  Schedule: grid-stride (R5 A/B: chunked -7%).
// R7 change (single A/B): 8192 -> 1024 blocks. Fill kernel evidence: 6.8TB/s
// at ~11% occupancy — compact lockstep moving front beats wide staggered
// concurrency. 1024 blocks = 4/CU, all co-resident, ~2MB write front.

typedef float f32x4 __attribute__((ext_vector_type(4)));
typedef float f32x2 __attribute__((ext_vector_type(2)));

__global__ __launch_bounds__(256) void upsample_pca3d_kernel(
    const float* __restrict__ x,
    const float* __restrict__ mean,
    const float* __restrict__ pca,
    float* __restrict__ out,
    int nj)                            // out_size/8 = 16777216
{
    float p[8], m[8];
#pragma unroll
    for (int k = 0; k < 8; ++k) { p[k] = pca[k]; m[k] = mean[k]; }

    const int tid = threadIdx.x;
    const int k1  = (tid >> 5) & 1;    // j bit 5 = Y bit 0; invariant per thread

    // k0 = 0 coefficients
    const float pA0 = k1 ? p[2] : p[0];
    const float pB0 = k1 ? p[3] : p[1];
    const float mA0 = k1 ? m[2] : m[0];
    const float mB0 = k1 ? m[3] : m[1];
    // k0 = 1 coefficients
    const float pA1 = k1 ? p[6] : p[4];
    const float pB1 = k1 ? p[7] : p[5];
    const float mA1 = k1 ? m[6] : m[4];
    const float mB1 = k1 ? m[7] : m[5];

    const f32x2* __restrict__ x2 = reinterpret_cast<const f32x2*>(x);
    f32x4* __restrict__ out4 = reinterpret_cast<f32x4*>(out);

    const int stride = gridDim.x * blockDim.x;
#pragma unroll 2
    for (int j = blockIdx.x * blockDim.x + tid; j < nj; j += stride) {
        const int Z4 = j & 31;
        const int Y  = (j >> 5) & 127;
        const int d  = (j >> 12) & 63;
        const int bc = j >> 18;

        const int xi = (bc << 17) + (d << 11) + ((Y >> 1) << 5) + Z4;
        const f32x2 v = __builtin_nontemporal_load(x2 + xi);

        const int o = (bc << 19) + (d << 13) + (Y << 5) + Z4;

        f32x4 o0, o1;
        o0.x = fmaf(v.x, pA0, mA0);
        o0.y = fmaf(v.x, pB0, mB0);
        o0.z = fmaf(v.y, pA0, mA0);
        o0.w = fmaf(v.y, pB0, mB0);
        o1.x = fmaf(v.x, pA1, mA1);
        o1.y = fmaf(v.x, pB1, mB1);
        o1.z = fmaf(v.y, pA1, mA1);
        o1.w = fmaf(v.y, pB1, mB1);

        __builtin_nontemporal_store(o0, out4 + o);           // k0 = 0 plane
        __builtin_nontemporal_store(o1, out4 + o + 4096);    // k0 = 1 plane (+64 KB)
    }
}

extern "C" void kernel_launch(void* const* d_in, const int* in_sizes, int n_in,
                              void* d_out, int out_size, void* d_ws, size_t ws_size,
                              hipStream_t stream) {
    const float* x    = (const float*)d_in[0];
    const float* mean = (const float*)d_in[1];
    const float* pca  = (const float*)d_in[2];
    float* out = (float*)d_out;

    const int nj = out_size / 8;       // 16777216 dual-float4 units
    const int threads = 256;
    const int blocks = 1024;           // 4 blocks/CU, all co-resident, 64 iters

    upsample_pca3d_kernel<<<blocks, threads, 0, stream>>>(x, mean, pca, out, nj);
}

// Round 8
// 112.030 us; speedup vs baseline: 1.1015x; 1.1015x over previous
//
#include <hip/hip_runtime.h>

// out[bc, 2d+k0, 2y+k1, 2z+k2] = x[bc,d,y,z] * p[k0*4+k1*2+k2] + m[...]
// x: (64,64,64,64) fp32, out: (64,128,128,128) fp32.
//
// Thread-unit j: reads x float2 once (NT load), writes dense float4 to both
// k0 planes (out4[o], out4[o+4096]).  j bits: bc(6) | d(6) | Y(7) | Z4(5).
//
// Locked-in from A/Bs: NT stores (R6: plain -6%), NT load, grid-stride
// mapping (R5 chunked -7%), 8192 blocks (R7 1024 -9%).
// R8 change (single A/B): batch the 8 grid-stride iterations into
// 8 loads -> 16 stores per thread (one R-burst then one W-burst) to cut
// DRAM read/write turnaround frequency 8x vs per-iteration alternation.

typedef float f32x4 __attribute__((ext_vector_type(4)));
typedef float f32x2 __attribute__((ext_vector_type(2)));

#define NBLK   8192
#define NITER  8                       // 8192*256*8 = 16777216 j-units

__global__ __launch_bounds__(256) void upsample_pca3d_kernel(
    const float* __restrict__ x,
    const float* __restrict__ mean,
    const float* __restrict__ pca,
    float* __restrict__ out)
{
    float p[8], m[8];
#pragma unroll
    for (int k = 0; k < 8; ++k) { p[k] = pca[k]; m[k] = mean[k]; }

    const int tid = threadIdx.x;
    const int k1  = (tid >> 5) & 1;    // j bit 5 = Y bit 0; invariant per thread

    const float pA0 = k1 ? p[2] : p[0];
    const float pB0 = k1 ? p[3] : p[1];
    const float mA0 = k1 ? m[2] : m[0];
    const float mB0 = k1 ? m[3] : m[1];
    const float pA1 = k1 ? p[6] : p[4];
    const float pB1 = k1 ? p[7] : p[5];
    const float mA1 = k1 ? m[6] : m[4];
    const float mB1 = k1 ? m[7] : m[5];

    const f32x2* __restrict__ x2 = reinterpret_cast<const f32x2*>(x);
    f32x4* __restrict__ out4 = reinterpret_cast<f32x4*>(out);

    const int j0 = blockIdx.x * 256 + tid;   // iteration stride = NBLK*256

    // Phase 1: read burst — 8 independent NT loads, statically indexed array.
    f32x2 v[NITER];
#pragma unroll
    for (int it = 0; it < NITER; ++it) {
        const int j  = j0 + it * (NBLK * 256);
        const int Z4 = j & 31;
        const int Y  = (j >> 5) & 127;
        const int d  = (j >> 12) & 63;
        const int bc = j >> 18;
        const int xi = (bc << 17) + (d << 11) + ((Y >> 1) << 5) + Z4;
        v[it] = __builtin_nontemporal_load(x2 + xi);
    }

    // Phase 2: write burst — 16 NT stores.
#pragma unroll
    for (int it = 0; it < NITER; ++it) {
        const int j  = j0 + it * (NBLK * 256);
        const int Z4 = j & 31;
        const int Y  = (j >> 5) & 127;
        const int d  = (j >> 12) & 63;
        const int bc = j >> 18;
        const int o  = (bc << 19) + (d << 13) + (Y << 5) + Z4;

        f32x4 o0, o1;
        o0.x = fmaf(v[it].x, pA0, mA0);
        o0.y = fmaf(v[it].x, pB0, mB0);
        o0.z = fmaf(v[it].y, pA0, mA0);
        o0.w = fmaf(v[it].y, pB0, mB0);
        o1.x = fmaf(v[it].x, pA1, mA1);
        o1.y = fmaf(v[it].x, pB1, mB1);
        o1.z = fmaf(v[it].y, pA1, mA1);
        o1.w = fmaf(v[it].y, pB1, mB1);

        __builtin_nontemporal_store(o0, out4 + o);           // k0 = 0 plane
        __builtin_nontemporal_store(o1, out4 + o + 4096);    // k0 = 1 plane
    }
}

extern "C" void kernel_launch(void* const* d_in, const int* in_sizes, int n_in,
                              void* d_out, int out_size, void* d_ws, size_t ws_size,
                              hipStream_t stream) {
    const float* x    = (const float*)d_in[0];
    const float* mean = (const float*)d_in[1];
    const float* pca  = (const float*)d_in[2];
    float* out = (float*)d_out;

    upsample_pca3d_kernel<<<NBLK, 256, 0, stream>>>(x, mean, pca, out);
}